// Round 5
// baseline (486.905 us; speedup 1.0000x reference)
//
#include <hip/hip_runtime.h>
#include <hip/hip_bf16.h>

// Problem constants
#define Bb 2
#define Ss 2048
#define DMD 2048
#define Hh 32
#define KVh 8
#define HD 64
// GQA groups = H/KV = 4. Inputs/outputs fp32.

using bf16 = __hip_bfloat16;
typedef __attribute__((ext_vector_type(8))) short short8;
typedef __attribute__((ext_vector_type(4))) short short4v;
typedef __attribute__((ext_vector_type(4))) float floatx4;

__device__ inline float tof(const bf16 x) { return __bfloat162float(x); }
__device__ inline void stor(float* p, float v) { *p = v; }
__device__ inline void stor(bf16* p, float v) { *p = __float2bfloat16(v); }
__device__ inline short bf16bits(float v) {
    union { bf16 h; short s; } cv; cv.h = __float2bfloat16(v); return cv.s;
}

// packed bf16 pair: low16 = bf16(lo), high16 = bf16(hi)
__device__ inline unsigned cvtpk_bf16(float lo, float hi) {
    unsigned r;
    asm("v_cvt_pk_bf16_f32 %0, %1, %2" : "=v"(r) : "v"(lo), "v"(hi));
    return r;
}

// global->LDS direct copy, 16 B per lane. LDS destination is the wave-uniform
// base; HW adds lane*16. (guide §5: width=16 is the 874-TF m97 staging path)
__device__ inline void gl_lds16(const bf16* g, bf16* l) {
    __builtin_amdgcn_global_load_lds(
        (const __attribute__((address_space(1))) unsigned int*)g,
        (__attribute__((address_space(3))) unsigned int*)l, 16, 0, 0);
}

// ---------------------------------------------------------------------------
// Prep pass 1: fp32 -> bf16 elementwise (8 elems/thread, float4 loads).
// ---------------------------------------------------------------------------
__global__ __launch_bounds__(256) void cvt_bf16_kernel(
    const float* __restrict__ in, bf16* __restrict__ out, int total8)
{
    const int i = blockIdx.x * 256 + threadIdx.x;
    if (i >= total8) return;
    const float4 a = ((const float4*)in)[2 * i];
    const float4 b = ((const float4*)in)[2 * i + 1];
    short8 r;
    r[0] = bf16bits(a.x); r[1] = bf16bits(a.y); r[2] = bf16bits(a.z); r[3] = bf16bits(a.w);
    r[4] = bf16bits(b.x); r[5] = bf16bits(b.y); r[6] = bf16bits(b.z); r[7] = bf16bits(b.w);
    ((short8*)out)[i] = r;
}

// ---------------------------------------------------------------------------
// Prep pass 2: W [K][N] fp32 -> Wt [rowOff+N][K] bf16 (transpose-convert),
// 32x32 LDS tile, 256 threads.
// ---------------------------------------------------------------------------
__global__ __launch_bounds__(256) void cvtT_kernel(
    const float* __restrict__ W, bf16* __restrict__ Wt,
    int N, int K, int rowOff)
{
    __shared__ float t[32][33];
    const int n0 = blockIdx.x * 32;
    const int k0 = blockIdx.y * 32;
    const int tx = threadIdx.x & 31, ty = threadIdx.x >> 5;   // ty 0..7
    #pragma unroll
    for (int r = 0; r < 32; r += 8)
        t[ty + r][tx] = W[(size_t)(k0 + ty + r) * N + n0 + tx];
    __syncthreads();
    #pragma unroll
    for (int r = 0; r < 32; r += 8)
        Wt[(size_t)(rowOff + n0 + ty + r) * K + k0 + tx] =
            __float2bfloat16(t[tx][ty + r]);
}

// ---------------------------------------------------------------------------
// MFMA GEMM, m97 structure: A [M][K] bf16 row-major, Bt [N][K] bf16 K-major.
// 128x128 tile, BK=32, 4 waves x (4x4 16x16x32 tiles), global_load_lds
// width-16 staging into linear [128][32] LDS tiles, 2-barrier loop.
// EPI 0: fused QKV scatter  (cols [0,2048)->Yq, [2048,2560)->Yk,
//        [2560,3072)->Yv transposed [b][kvh][d][s] with +bias)
// EPI 1: fp32 out + bias (O projection)
// ---------------------------------------------------------------------------
template <int EPI>
__global__ __launch_bounds__(256) void gemm_bt(
    const bf16* __restrict__ A, const bf16* __restrict__ Bt,
    const float* __restrict__ bias,
    bf16* __restrict__ Yq, bf16* __restrict__ Yk, bf16* __restrict__ Yv,
    float* __restrict__ Yo, int M, int N, int K)
{
    __shared__ bf16 As[128 * 32];   // [m][k] row-major, chunk ch <-> bytes ch*16
    __shared__ bf16 Bs[128 * 32];   // [n][k] row-major

    const int tid  = threadIdx.x;
    const int wave = tid >> 6, lane = tid & 63;
    const int lid  = lane & 15, quad = lane >> 4;
    const int wr = (wave >> 1) * 64, wc = (wave & 1) * 64;
    const size_t bm = (size_t)blockIdx.y * 128, bn = (size_t)blockIdx.x * 128;

    floatx4 acc[4][4];
    #pragma unroll
    for (int i = 0; i < 4; ++i)
        #pragma unroll
        for (int j = 0; j < 4; ++j)
            acc[i][j] = (floatx4){0.f, 0.f, 0.f, 0.f};

    for (int k0 = 0; k0 < K; k0 += 32) {
        // stage A-tile and B-tile: 512 16B-chunks each; wave covers 128
        // chunks (2 issues). chunk c: row = c>>2, k-col = (c&3)*8.
        #pragma unroll
        for (int i = 0; i < 2; ++i) {
            const int c   = wave * 128 + i * 64 + lane;
            const int row = c >> 2, col = (c & 3) * 8;
            gl_lds16(A  + (bm + row) * (size_t)K + k0 + col,
                     &As[(wave * 128 + i * 64) * 8]);
            gl_lds16(Bt + (bn + row) * (size_t)K + k0 + col,
                     &Bs[(wave * 128 + i * 64) * 8]);
        }
        __syncthreads();

        short8 af[4], bfr[4];
        #pragma unroll
        for (int i = 0; i < 4; ++i)
            af[i] = *(const short8*)&As[(wr + i * 16 + lid) * 32 + quad * 8];
        #pragma unroll
        for (int j = 0; j < 4; ++j)
            bfr[j] = *(const short8*)&Bs[(wc + j * 16 + lid) * 32 + quad * 8];
        #pragma unroll
        for (int i = 0; i < 4; ++i)
            #pragma unroll
            for (int j = 0; j < 4; ++j)
                acc[i][j] = __builtin_amdgcn_mfma_f32_16x16x32_bf16(
                    af[i], bfr[j], acc[i][j], 0, 0, 0);
        __syncthreads();
    }

    #pragma unroll
    for (int i = 0; i < 4; ++i) {
        const int gm0 = (int)bm + wr + i * 16 + quad * 4;
        #pragma unroll
        for (int j = 0; j < 4; ++j) {
            const int gn = (int)bn + wc + j * 16 + lid;
            #pragma unroll
            for (int r = 0; r < 4; ++r) {
                float v = acc[i][j][r];
                const int gm = gm0 + r;
                if (EPI == 0) {
                    if (gn < Hh * HD) {
                        stor(&Yq[(size_t)gm * (Hh * HD) + gn], v);
                    } else if (gn < Hh * HD + KVh * HD) {
                        stor(&Yk[(size_t)gm * (KVh * HD) + (gn - Hh * HD)], v);
                    } else {
                        const int c = gn - (Hh * HD + KVh * HD);
                        v += bias[c];
                        const int kvh = c >> 6, dd = c & 63;
                        const int bbi = gm >> 11, s = gm & (Ss - 1);
                        stor(&Yv[(((size_t)bbi * KVh + kvh) * HD + dd) * Ss + s], v);
                    }
                } else {
                    Yo[(size_t)gm * N + gn] = v + bias[gn];
                }
            }
        }
    }
}

// ---------------------------------------------------------------------------
// In-place RoPE on bf16 buf laid out [B*S][nheads][64]; fp32 cos/sin.
// scale: extra output multiplier (1/sqrt(HD) folded into Q).
// ---------------------------------------------------------------------------
__global__ void rope_kernel(bf16* __restrict__ buf,
                            const float* __restrict__ cosb,
                            const float* __restrict__ sinb,
                            int nheads, int total, float scale)
{
    int idx = blockIdx.x * blockDim.x + threadIdx.x;
    if (idx >= total) return;
    int d = idx & 31;
    int h = (idx >> 5) % nheads;
    int bs = idx / (32 * nheads);
    bf16* row = buf + ((size_t)bs * nheads + h) * HD;
    float x1 = tof(row[d]), x2 = tof(row[d + 32]);
    float c1 = cosb[(size_t)bs * HD + d];
    float s1 = sinb[(size_t)bs * HD + d];
    float c2 = cosb[(size_t)bs * HD + d + 32];
    float s2 = sinb[(size_t)bs * HD + d + 32];
    stor(&row[d],      (x1 * c1 - x2 * s1) * scale);
    stor(&row[d + 32], (x2 * c2 + x1 * s2) * scale);
}

// ---------------------------------------------------------------------------
// MFMA flash attention v5: swapped QK^T + in-register softmax + pi-folded PV.
// mfma(K,Q) puts S^T in C-layout with q = lid, k = nt*16+quad*4+reg, so the
// row-softmax is lane-local. The PV A-fragment is built IN-LANE: the per-32
// k-permutation pi(quad*8+j) = 32c + quad*4 + j (j<4) / 32c+16+quad*4+(j-4)
// (j>=4) is a bijection, so O = sum_k P[q][pi]V[pi][d] = P V; each lane's
// A-frag slots are exactly the P values it already holds (8 v_cvt_pk per
// group, zero cross-lane ops), and V's B-frag reads the matching two 8 B
// chunks per 32-k. No LDS/DS instruction anywhere in this kernel.
// Wave owns 32 q-rows; 1024 blocks heavy-first; kvh = bid%8 pins each
// KV-head's L2 set to one XCD.
// ---------------------------------------------------------------------------
template <bool CAUSAL>
__device__ __forceinline__ void fattn_tile(
    const int k0, const int m0,
    const bf16* __restrict__ kBase, const bf16* __restrict__ vBase,
    const int* __restrict__ mBase,
    const short8 qf0[2], const short8 qf1[2],
    floatx4 o[2][4], float lsum[2],
    const int lid, const int quad)
{
    const size_t kStride = (size_t)KVh * HD;  // 512 elems

    // ---- K A-fragments: K[k = nt*16+lid][d-chunk quad*8] ----
    short8 ka0[4], ka1[4];
    #pragma unroll
    for (int nt = 0; nt < 4; ++nt) {
        const bf16* kr = kBase + (size_t)(k0 + nt * 16 + lid) * kStride + quad * 8;
        ka0[nt] = *(const short8*)(kr);
        ka1[nt] = *(const short8*)(kr + 32);
    }

    // ---- S^T = K Q^T: C[k][q], q = lid, k = nt*16 + quad*4 + reg ----
    floatx4 st[2][4];
    __builtin_amdgcn_s_setprio(1);
    #pragma unroll
    for (int nt = 0; nt < 4; ++nt)
        #pragma unroll
        for (int g = 0; g < 2; ++g) {
            floatx4 c = (floatx4){0.f, 0.f, 0.f, 0.f};
            c = __builtin_amdgcn_mfma_f32_16x16x32_bf16(ka0[nt], qf0[g], c, 0, 0, 0);
            c = __builtin_amdgcn_mfma_f32_16x16x32_bf16(ka1[nt], qf1[g], c, 0, 0, 0);
            st[g][nt] = c;
        }
    __builtin_amdgcn_s_setprio(0);

    // ---- V B-fragments (pi-reordered), issued early to hide under softmax.
    // B-frag slot (quad, j): V[k = k0 + 32c + quad*4 + j(<4) | +16+(j-4)][d].
    union vbu { short4v h[2]; short8 s8; };
    vbu vb[4][2];
    #pragma unroll
    for (int dt = 0; dt < 4; ++dt)
        #pragma unroll
        for (int c = 0; c < 2; ++c) {
            const bf16* vr = vBase + (size_t)(dt * 16 + lid) * Ss
                           + k0 + c * 32 + quad * 4;
            vb[dt][c].h[0] = *(const short4v*)(vr);
            vb[dt][c].h[1] = *(const short4v*)(vr + 16);
        }

    // ---- attention mask, per-quad int4 (k = k0+nt*16+quad*4 ..+3) ----
    int mk[4][4];
    #pragma unroll
    for (int nt = 0; nt < 4; ++nt) {
        const int4 m4 = *(const int4*)(mBase + k0 + nt * 16 + quad * 4);
        mk[nt][0] = m4.x; mk[nt][1] = m4.y; mk[nt][2] = m4.z; mk[nt][3] = m4.w;
    }

    // ---- mask + exp; lane-local row sums (q = lid) ----
    #pragma unroll
    for (int g = 0; g < 2; ++g) {
        const int qrow = m0 + g * 16 + lid;
        #pragma unroll
        for (int nt = 0; nt < 4; ++nt)
            #pragma unroll
            for (int r = 0; r < 4; ++r) {
                const int kcol = k0 + nt * 16 + quad * 4 + r;
                const float p = (mk[nt][r] == 0 || (CAUSAL && kcol > qrow))
                              ? 0.f : __expf(st[g][nt][r]);
                st[g][nt][r] = p;
                lsum[g] += p;
            }
    }

    // ---- P pack (in-lane, pi-ordered) + PV ----
    #pragma unroll
    for (int g = 0; g < 2; ++g) {
        // A-frag chunk c, word m: j = {2m, 2m+1}; source st[g][2c + (m>>1)].
        union { unsigned u[4]; short8 s; } pf[2];
        #pragma unroll
        for (int c = 0; c < 2; ++c) {
            pf[c].u[0] = cvtpk_bf16(st[g][2 * c][0],     st[g][2 * c][1]);
            pf[c].u[1] = cvtpk_bf16(st[g][2 * c][2],     st[g][2 * c][3]);
            pf[c].u[2] = cvtpk_bf16(st[g][2 * c + 1][0], st[g][2 * c + 1][1]);
            pf[c].u[3] = cvtpk_bf16(st[g][2 * c + 1][2], st[g][2 * c + 1][3]);
        }
        // O[q][d]: row = quad*4+reg = q, col = dt*16+lid = d
        __builtin_amdgcn_s_setprio(1);
        #pragma unroll
        for (int dt = 0; dt < 4; ++dt) {
            o[g][dt] = __builtin_amdgcn_mfma_f32_16x16x32_bf16(
                pf[0].s, vb[dt][0].s8, o[g][dt], 0, 0, 0);
            o[g][dt] = __builtin_amdgcn_mfma_f32_16x16x32_bf16(
                pf[1].s, vb[dt][1].s8, o[g][dt], 0, 0, 0);
        }
        __builtin_amdgcn_s_setprio(0);
    }
}

__global__ __launch_bounds__(256) void fattn_kernel(
    bf16* __restrict__ QO, const bf16* __restrict__ Kb,
    const bf16* __restrict__ Vt, const int* __restrict__ mask)
{
    const int bid    = blockIdx.x;      // 0..1023
    const int kvh    = bid & 7;         // XCD-local K/V reuse
    const int rest   = bid >> 3;        // 0..127
    const int qbslot = rest >> 3;       // 0..15, 0 launches first
    const int bh     = rest & 7;
    const int hg     = bh & 3;
    const int b      = bh >> 2;
    const int qb     = 15 - qbslot;     // heavy q-superblocks first
    const int h      = kvh * 4 + hg;

    const int tid  = threadIdx.x;
    const int wave = tid >> 6;
    const int lane = tid & 63;
    const int lid  = lane & 15;
    const int quad = lane >> 4;

    const int qw = qb * 4 + wave;       // 0..63, this wave's 32-row q-block
    const int m0 = qw * 32;
    const int nfull = qw >> 1;          // fully-causal-valid 64-key tiles

    const size_t kStride = (size_t)KVh * HD;  // 512 elems
    const bf16* kBase = Kb + ((size_t)b * Ss) * kStride + (size_t)kvh * HD;
    const bf16* vBase = Vt + ((size_t)(b * KVh + kvh) * HD) * Ss;
    const int*  mBase = mask + b * Ss;

    // Q fragments, used as the MFMA B-operand (col = q = lid, contraction d)
    short8 qf0[2], qf1[2];
    #pragma unroll
    for (int g = 0; g < 2; ++g) {
        const bf16* qb_ = QO + ((size_t)(b * Ss + m0 + g * 16 + lid) * Hh + h) * HD
                        + quad * 8;
        qf0[g] = *(const short8*)(qb_);
        qf1[g] = *(const short8*)(qb_ + 32);
    }

    floatx4 o[2][4];
    float lsum[2] = {0.f, 0.f};
    #pragma unroll
    for (int g = 0; g < 2; ++g)
        #pragma unroll
        for (int dt = 0; dt < 4; ++dt) o[g][dt] = (floatx4){0.f, 0.f, 0.f, 0.f};

    // Full tiles: attention_mask check only.
    for (int kt = 0; kt < nfull; ++kt)
        fattn_tile<false>(kt * 64, m0, kBase, vBase, mBase,
                          qf0, qf1, o, lsum, lid, quad);
    // Boundary tile: causal + attention_mask.
    fattn_tile<true>(nfull * 64, m0, kBase, vBase, mBase,
                     qf0, qf1, o, lsum, lid, quad);

    // ---- epilogue: quad-reduce l (q = lid), redistribute, normalize ----
    #pragma unroll
    for (int g = 0; g < 2; ++g) {
        float rs = lsum[g];
        rs += __shfl_xor(rs, 16);
        rs += __shfl_xor(rs, 32);
        const float inv = 1.f / rs;
        #pragma unroll
        for (int reg = 0; reg < 4; ++reg) {
            const float invr = __shfl(inv, quad * 4 + reg);  // sum for q-row
            const int m = m0 + g * 16 + quad * 4 + reg;
            bf16* orow = QO + ((size_t)(b * Ss + m) * Hh + h) * HD;
            #pragma unroll
            for (int dt = 0; dt < 4; ++dt)
                stor(&orow[dt * 16 + lid], o[g][dt][reg] * invr);
        }
    }
}

// ---------------------------------------------------------------------------
extern "C" void kernel_launch(void* const* d_in, const int* in_sizes, int n_in,
                              void* d_out, int out_size, void* d_ws, size_t ws_size,
                              hipStream_t stream)
{
    const float* hs   = (const float*)d_in[0];
    const int*   mask = (const int*)d_in[1];
    const float* cosb = (const float*)d_in[2];
    const float* sinb = (const float*)d_in[3];
    const float* Wq   = (const float*)d_in[4];
    const float* Wk   = (const float*)d_in[5];
    const float* Wv   = (const float*)d_in[6];
    const float* bv   = (const float*)d_in[7];
    const float* Wo   = (const float*)d_in[8];
    const float* bo   = (const float*)d_in[9];
    float* out = (float*)d_out;

    const int M = Bb * Ss;  // 4096

    // Workspace (37.75 MB): QO bf16 [M][2048] (16.8 MB) + Wqkv_t bf16
    // [3072][2048] (12.6 MB) + Wo_t bf16 [2048][2048] (8.4 MB).
    bf16* QO    = (bf16*)d_ws;
    bf16* Wqkvt = QO + (size_t)M * (Hh * HD);
    bf16* Wot   = Wqkvt + (size_t)3072 * DMD;

    // d_out scratch (25.2 MB of 33.5 MB): Kb, Vt (front), Abf (middle).
    // All three are dead before the O-projection overwrites d_out.
    bf16* Kb  = (bf16*)d_out;
    bf16* Vt  = Kb + (size_t)M * (KVh * HD);
    bf16* Abf = Vt + (size_t)M * (KVh * HD);

    dim3 blk(256);

    // Prep: hs -> bf16; weights -> K-major bf16 (Wq|Wk|Wv concatenated).
    const int total8 = M * DMD / 8;
    cvt_bf16_kernel<<<(total8 + 255) / 256, blk, 0, stream>>>(hs, Abf, total8);
    cvtT_kernel<<<dim3((Hh * HD) / 32, DMD / 32), blk, 0, stream>>>(
        Wq, Wqkvt, Hh * HD, DMD, 0);
    cvtT_kernel<<<dim3((KVh * HD) / 32, DMD / 32), blk, 0, stream>>>(
        Wk, Wqkvt, KVh * HD, DMD, Hh * HD);
    cvtT_kernel<<<dim3((KVh * HD) / 32, DMD / 32), blk, 0, stream>>>(
        Wv, Wqkvt, KVh * HD, DMD, Hh * HD + KVh * HD);
    cvtT_kernel<<<dim3(DMD / 32, DMD / 32), blk, 0, stream>>>(
        Wo, Wot, DMD, DMD, 0);

    // Fused QKV projection (bf16 in, bf16 staged out; V transposed +bias).
    gemm_bt<0><<<dim3(3072 / 128, M / 128), blk, 0, stream>>>(
        Abf, Wqkvt, bv, QO, Kb, Vt, nullptr, M, 3072, DMD);

    // RoPE (in place; Q gets the 1/sqrt(HD) softmax scale folded in)
    int totq = M * Hh * 32, totk = M * KVh * 32;
    rope_kernel<<<(totq + 255) / 256, blk, 0, stream>>>(QO, cosb, sinb, Hh, totq, 0.125f);
    rope_kernel<<<(totk + 255) / 256, blk, 0, stream>>>(Kb, cosb, sinb, KVh, totk, 1.0f);

    // Flash attention v5 (O overwrites Q in place); 1024 blocks, 1 q-block/wave.
    fattn_kernel<<<dim3(1024), blk, 0, stream>>>(QO, Kb, Vt, mask);

    // Output projection (+bias, fp32 out)
    gemm_bt<1><<<dim3(DMD / 128, M / 128), blk, 0, stream>>>(
        QO, Wot, bo, nullptr, nullptr, nullptr, out, M, DMD, DMD);
}

// Round 6
// 429.836 us; speedup vs baseline: 1.1328x; 1.1328x over previous
//
#include <hip/hip_runtime.h>
#include <hip/hip_bf16.h>

// Problem constants
#define Bb 2
#define Ss 2048
#define DMD 2048
#define Hh 32
#define KVh 8
#define HD 64
// GQA groups = H/KV = 4. Inputs/outputs fp32.

using bf16 = __hip_bfloat16;
typedef __attribute__((ext_vector_type(8))) short short8;
typedef __attribute__((ext_vector_type(4))) float floatx4;

__device__ inline float tof(const bf16 x) { return __bfloat162float(x); }
__device__ inline void stor(float* p, float v) { *p = v; }
__device__ inline void stor(bf16* p, float v) { *p = __float2bfloat16(v); }
__device__ inline short bf16bits(float v) {
    union { bf16 h; short s; } cv; cv.h = __float2bfloat16(v); return cv.s;
}

// global->LDS direct copy, 16 B per lane. LDS destination is the wave-uniform
// base; HW adds lane*16. (guide §5: width=16 is the 874-TF m97 staging path)
__device__ inline void gl_lds16(const bf16* g, bf16* l) {
    __builtin_amdgcn_global_load_lds(
        (const __attribute__((address_space(1))) unsigned int*)g,
        (__attribute__((address_space(3))) unsigned int*)l, 16, 0, 0);
}

// ---------------------------------------------------------------------------
// Prep pass 1: fp32 -> bf16 elementwise (8 elems/thread, float4 loads).
// ---------------------------------------------------------------------------
__global__ __launch_bounds__(256) void cvt_bf16_kernel(
    const float* __restrict__ in, bf16* __restrict__ out, int total8)
{
    const int i = blockIdx.x * 256 + threadIdx.x;
    if (i >= total8) return;
    const float4 a = ((const float4*)in)[2 * i];
    const float4 b = ((const float4*)in)[2 * i + 1];
    short8 r;
    r[0] = bf16bits(a.x); r[1] = bf16bits(a.y); r[2] = bf16bits(a.z); r[3] = bf16bits(a.w);
    r[4] = bf16bits(b.x); r[5] = bf16bits(b.y); r[6] = bf16bits(b.z); r[7] = bf16bits(b.w);
    ((short8*)out)[i] = r;
}

// ---------------------------------------------------------------------------
// Prep pass 2: W [K][N] fp32 -> Wt [rowOff+N][K] bf16 (transpose-convert),
// 32x32 LDS tile, 256 threads.
// ---------------------------------------------------------------------------
__global__ __launch_bounds__(256) void cvtT_kernel(
    const float* __restrict__ W, bf16* __restrict__ Wt,
    int N, int K, int rowOff)
{
    __shared__ float t[32][33];
    const int n0 = blockIdx.x * 32;
    const int k0 = blockIdx.y * 32;
    const int tx = threadIdx.x & 31, ty = threadIdx.x >> 5;   // ty 0..7
    #pragma unroll
    for (int r = 0; r < 32; r += 8)
        t[ty + r][tx] = W[(size_t)(k0 + ty + r) * N + n0 + tx];
    __syncthreads();
    #pragma unroll
    for (int r = 0; r < 32; r += 8)
        Wt[(size_t)(rowOff + n0 + ty + r) * K + k0 + tx] =
            __float2bfloat16(t[tx][ty + r]);
}

// ---------------------------------------------------------------------------
// MFMA GEMM, m97 structure: A [M][K] bf16 row-major, Bt [N][K] bf16 K-major.
// 128x128 tile, BK=32, 4 waves x (4x4 16x16x32 tiles), global_load_lds
// width-16 staging into linear [128][32] LDS tiles, 2-barrier loop.
// EPI 0: fused QKV scatter  (cols [0,2048)->Yq, [2048,2560)->Yk,
//        [2560,3072)->Yv transposed [b][kvh][d][s] with +bias)
// EPI 1: fp32 out + bias (O projection)
// ---------------------------------------------------------------------------
template <int EPI>
__global__ __launch_bounds__(256) void gemm_bt(
    const bf16* __restrict__ A, const bf16* __restrict__ Bt,
    const float* __restrict__ bias,
    bf16* __restrict__ Yq, bf16* __restrict__ Yk, bf16* __restrict__ Yv,
    float* __restrict__ Yo, int M, int N, int K)
{
    __shared__ bf16 As[128 * 32];   // [m][k] row-major, chunk ch <-> bytes ch*16
    __shared__ bf16 Bs[128 * 32];   // [n][k] row-major

    const int tid  = threadIdx.x;
    const int wave = tid >> 6, lane = tid & 63;
    const int lid  = lane & 15, quad = lane >> 4;
    const int wr = (wave >> 1) * 64, wc = (wave & 1) * 64;
    const size_t bm = (size_t)blockIdx.y * 128, bn = (size_t)blockIdx.x * 128;

    floatx4 acc[4][4];
    #pragma unroll
    for (int i = 0; i < 4; ++i)
        #pragma unroll
        for (int j = 0; j < 4; ++j)
            acc[i][j] = (floatx4){0.f, 0.f, 0.f, 0.f};

    for (int k0 = 0; k0 < K; k0 += 32) {
        // stage A-tile and B-tile: 512 16B-chunks each; wave covers 128
        // chunks (2 issues). chunk c: row = c>>2, k-col = (c&3)*8.
        #pragma unroll
        for (int i = 0; i < 2; ++i) {
            const int c   = wave * 128 + i * 64 + lane;
            const int row = c >> 2, col = (c & 3) * 8;
            gl_lds16(A  + (bm + row) * (size_t)K + k0 + col,
                     &As[(wave * 128 + i * 64) * 8]);
            gl_lds16(Bt + (bn + row) * (size_t)K + k0 + col,
                     &Bs[(wave * 128 + i * 64) * 8]);
        }
        __syncthreads();

        short8 af[4], bfr[4];
        #pragma unroll
        for (int i = 0; i < 4; ++i)
            af[i] = *(const short8*)&As[(wr + i * 16 + lid) * 32 + quad * 8];
        #pragma unroll
        for (int j = 0; j < 4; ++j)
            bfr[j] = *(const short8*)&Bs[(wc + j * 16 + lid) * 32 + quad * 8];
        #pragma unroll
        for (int i = 0; i < 4; ++i)
            #pragma unroll
            for (int j = 0; j < 4; ++j)
                acc[i][j] = __builtin_amdgcn_mfma_f32_16x16x32_bf16(
                    af[i], bfr[j], acc[i][j], 0, 0, 0);
        __syncthreads();
    }

    #pragma unroll
    for (int i = 0; i < 4; ++i) {
        const int gm0 = (int)bm + wr + i * 16 + quad * 4;
        #pragma unroll
        for (int j = 0; j < 4; ++j) {
            const int gn = (int)bn + wc + j * 16 + lid;
            #pragma unroll
            for (int r = 0; r < 4; ++r) {
                float v = acc[i][j][r];
                const int gm = gm0 + r;
                if (EPI == 0) {
                    if (gn < Hh * HD) {
                        stor(&Yq[(size_t)gm * (Hh * HD) + gn], v);
                    } else if (gn < Hh * HD + KVh * HD) {
                        stor(&Yk[(size_t)gm * (KVh * HD) + (gn - Hh * HD)], v);
                    } else {
                        const int c = gn - (Hh * HD + KVh * HD);
                        v += bias[c];
                        const int kvh = c >> 6, dd = c & 63;
                        const int bbi = gm >> 11, s = gm & (Ss - 1);
                        stor(&Yv[(((size_t)bbi * KVh + kvh) * HD + dd) * Ss + s], v);
                    }
                } else {
                    Yo[(size_t)gm * N + gn] = v + bias[gn];
                }
            }
        }
    }
}

// ---------------------------------------------------------------------------
// In-place RoPE on bf16 buf laid out [B*S][nheads][64]; fp32 cos/sin.
// scale: extra output multiplier (1/sqrt(HD) folded into Q).
// ---------------------------------------------------------------------------
__global__ void rope_kernel(bf16* __restrict__ buf,
                            const float* __restrict__ cosb,
                            const float* __restrict__ sinb,
                            int nheads, int total, float scale)
{
    int idx = blockIdx.x * blockDim.x + threadIdx.x;
    if (idx >= total) return;
    int d = idx & 31;
    int h = (idx >> 5) % nheads;
    int bs = idx / (32 * nheads);
    bf16* row = buf + ((size_t)bs * nheads + h) * HD;
    float x1 = tof(row[d]), x2 = tof(row[d + 32]);
    float c1 = cosb[(size_t)bs * HD + d];
    float s1 = sinb[(size_t)bs * HD + d];
    float c2 = cosb[(size_t)bs * HD + d + 32];
    float s2 = sinb[(size_t)bs * HD + d + 32];
    stor(&row[d],      (x1 * c1 - x2 * s1) * scale);
    stor(&row[d + 32], (x2 * c2 + x1 * s2) * scale);
}

// ---------------------------------------------------------------------------
// MFMA flash attention v6: v3 structure (best measured: 136.6 us) + two
// fixes. (1) K-fragment register prefetch: tile t+1's 8x16B K loads issue
// before tile t's compute, so K latency hides under QK+softmax+pLds+PV —
// the counted-vmcnt pipeline the compiler emits for in-flight loads.
// (2) pLds row pad 72 -> 76 shorts: quad-group bank bases become
// {0,24,16,8} mod 32 (disjoint) instead of {0,16,0,16} (4-way) — kills the
// 1.08M bank-conflict cycles on the P-transpose writes and the lid/lid+8
// read collisions. Everything else as v3: one 32-row q-block per wave, 1024
// blocks heavy-first, kvh = bid%8 XCD pinning, causal only on boundary
// tile, setprio around MFMA clusters, no __syncthreads.
// ---------------------------------------------------------------------------
struct KFrag { short8 a0[4], a1[4]; };

__device__ __forceinline__ void load_kfrag(
    const bf16* __restrict__ kBase, const int k0,
    const int lid, const int quad, KFrag& f)
{
    const size_t kStride = (size_t)KVh * HD;  // 512 elems
    #pragma unroll
    for (int nt = 0; nt < 4; ++nt) {
        const bf16* kr = kBase + (size_t)(k0 + nt * 16 + lid) * kStride + quad * 8;
        f.a0[nt] = *(const short8*)(kr);
        f.a1[nt] = *(const short8*)(kr + 32);
    }
}

template <bool CAUSAL>
__device__ __forceinline__ void fattn_tile(
    const KFrag& kf, const int k0, const int m0,
    const bf16* __restrict__ vBase, const int* __restrict__ mBase,
    const short8 qf0[2], const short8 qf1[2],
    floatx4 o[2][4], float lsum[2][4],
    short (*pw)[16][76],               // -> pLds[wave]: [2][16][76]
    const int lid, const int quad)
{
    // ---- S = Q K^T (K from prefetched registers) ----
    floatx4 s[2][4];
    __builtin_amdgcn_s_setprio(1);
    #pragma unroll
    for (int nt = 0; nt < 4; ++nt)
        #pragma unroll
        for (int g = 0; g < 2; ++g) {
            floatx4 c = (floatx4){0.f, 0.f, 0.f, 0.f};
            c = __builtin_amdgcn_mfma_f32_16x16x32_bf16(qf0[g], kf.a0[nt], c, 0, 0, 0);
            c = __builtin_amdgcn_mfma_f32_16x16x32_bf16(qf1[g], kf.a1[nt], c, 0, 0, 0);
            s[g][nt] = c;
        }
    __builtin_amdgcn_s_setprio(0);

    // ---- V fragment loads issue here; latency hides under softmax ----
    short8 vb0[4], vb1[4];
    #pragma unroll
    for (int nt = 0; nt < 4; ++nt) {
        const bf16* vr = vBase + (size_t)(nt * 16 + lid) * Ss + k0 + quad * 8;
        vb0[nt] = *(const short8*)(vr);
        vb1[nt] = *(const short8*)(vr + 32);
    }

    // ---- mask + exp; per-lane row-sum partials ----
    #pragma unroll
    for (int nt = 0; nt < 4; ++nt) {
        const int col = k0 + nt * 16 + lid;
        const int mk  = mBase[col];
        #pragma unroll
        for (int g = 0; g < 2; ++g) {
            const int mr0 = m0 + g * 16 + quad * 4;
            #pragma unroll
            for (int rr = 0; rr < 4; ++rr) {
                float p;
                if (CAUSAL)
                    p = (mk == 0 || col > mr0 + rr) ? 0.f : __expf(s[g][nt][rr]);
                else
                    p = (mk == 0) ? 0.f : __expf(s[g][nt][rr]);
                s[g][nt][rr] = p;
                lsum[g][rr] += p;
            }
        }
    }

    // ---- P: C-layout -> A-layout via per-wave private LDS (pad 76) ----
    #pragma unroll
    for (int g = 0; g < 2; ++g)
        #pragma unroll
        for (int nt = 0; nt < 4; ++nt)
            #pragma unroll
            for (int rr = 0; rr < 4; ++rr)
                pw[g][quad * 4 + rr][nt * 16 + lid] = bf16bits(s[g][nt][rr]);
    short8 pf0[2], pf1[2];
    #pragma unroll
    for (int g = 0; g < 2; ++g) {
        pf0[g] = *(const short8*)&pw[g][lid][quad * 8];
        pf1[g] = *(const short8*)&pw[g][lid][32 + quad * 8];
    }

    // ---- O += P V ----
    __builtin_amdgcn_s_setprio(1);
    #pragma unroll
    for (int nt = 0; nt < 4; ++nt)
        #pragma unroll
        for (int g = 0; g < 2; ++g) {
            o[g][nt] = __builtin_amdgcn_mfma_f32_16x16x32_bf16(
                pf0[g], vb0[nt], o[g][nt], 0, 0, 0);
            o[g][nt] = __builtin_amdgcn_mfma_f32_16x16x32_bf16(
                pf1[g], vb1[nt], o[g][nt], 0, 0, 0);
        }
    __builtin_amdgcn_s_setprio(0);
}

__global__ __launch_bounds__(256) void fattn_kernel(
    bf16* __restrict__ QO, const bf16* __restrict__ Kb,
    const bf16* __restrict__ Vt, const int* __restrict__ mask)
{
    const int bid    = blockIdx.x;      // 0..1023
    const int kvh    = bid & 7;         // XCD-local K/V reuse
    const int rest   = bid >> 3;        // 0..127
    const int qbslot = rest >> 3;       // 0..15, 0 launches first
    const int bh     = rest & 7;
    const int hg     = bh & 3;
    const int b      = bh >> 2;
    const int qb     = 15 - qbslot;     // heavy q-superblocks first
    const int h      = kvh * 4 + hg;

    const int tid  = threadIdx.x;
    const int wave = tid >> 6;
    const int lane = tid & 63;
    const int lid  = lane & 15;
    const int quad = lane >> 4;

    const int qw = qb * 4 + wave;       // 0..63, this wave's 32-row q-block
    const int m0 = qw * 32;
    const int nfull = qw >> 1;          // fully-causal-valid 64-key tiles

    __shared__ short pLds[4][2][16][76];   // per-wave private P transpose

    const size_t kStride = (size_t)KVh * HD;  // 512 elems
    const bf16* kBase = Kb + ((size_t)b * Ss) * kStride + (size_t)kvh * HD;
    const bf16* vBase = Vt + ((size_t)(b * KVh + kvh) * HD) * Ss;
    const int*  mBase = mask + b * Ss;

    // Q fragments for both 16-row groups (pre-scaled by 1/8 in rope)
    short8 qf0[2], qf1[2];
    #pragma unroll
    for (int g = 0; g < 2; ++g) {
        const bf16* qb_ = QO + ((size_t)(b * Ss + m0 + g * 16 + lid) * Hh + h) * HD
                        + quad * 8;
        qf0[g] = *(const short8*)(qb_);
        qf1[g] = *(const short8*)(qb_ + 32);
    }

    floatx4 o[2][4];
    float lsum[2][4];
    #pragma unroll
    for (int g = 0; g < 2; ++g) {
        #pragma unroll
        for (int nt = 0; nt < 4; ++nt) o[g][nt] = (floatx4){0.f, 0.f, 0.f, 0.f};
        #pragma unroll
        for (int rr = 0; rr < 4; ++rr) lsum[g][rr] = 0.f;
    }

    // ---- 2-deep K prefetch pipeline over full tiles + boundary tile ----
    KFrag fA, fB;
    load_kfrag(kBase, 0, lid, quad, fA);
    bool inA = true;
    for (int kt = 0; kt < nfull; ++kt) {
        const int k0 = kt * 64;
        if (inA) {
            load_kfrag(kBase, k0 + 64, lid, quad, fB);
            fattn_tile<false>(fA, k0, m0, vBase, mBase,
                              qf0, qf1, o, lsum, pLds[wave], lid, quad);
        } else {
            load_kfrag(kBase, k0 + 64, lid, quad, fA);
            fattn_tile<false>(fB, k0, m0, vBase, mBase,
                              qf0, qf1, o, lsum, pLds[wave], lid, quad);
        }
        inA = !inA;
    }
    if (inA)
        fattn_tile<true>(fA, nfull * 64, m0, vBase, mBase,
                         qf0, qf1, o, lsum, pLds[wave], lid, quad);
    else
        fattn_tile<true>(fB, nfull * 64, m0, vBase, mBase,
                         qf0, qf1, o, lsum, pLds[wave], lid, quad);

    // ---- epilogue: reduce l across the 16 key-lanes, normalize, store ----
    #pragma unroll
    for (int g = 0; g < 2; ++g)
        #pragma unroll
        for (int rr = 0; rr < 4; ++rr) {
            float rs = lsum[g][rr];
            rs += __shfl_xor(rs, 1);
            rs += __shfl_xor(rs, 2);
            rs += __shfl_xor(rs, 4);
            rs += __shfl_xor(rs, 8);
            const float inv = 1.f / rs;
            const int m = m0 + g * 16 + quad * 4 + rr;
            bf16* orow = QO + ((size_t)(b * Ss + m) * Hh + h) * HD;
            #pragma unroll
            for (int nt = 0; nt < 4; ++nt)
                stor(&orow[nt * 16 + lid], o[g][nt][rr] * inv);
        }
}

// ---------------------------------------------------------------------------
extern "C" void kernel_launch(void* const* d_in, const int* in_sizes, int n_in,
                              void* d_out, int out_size, void* d_ws, size_t ws_size,
                              hipStream_t stream)
{
    const float* hs   = (const float*)d_in[0];
    const int*   mask = (const int*)d_in[1];
    const float* cosb = (const float*)d_in[2];
    const float* sinb = (const float*)d_in[3];
    const float* Wq   = (const float*)d_in[4];
    const float* Wk   = (const float*)d_in[5];
    const float* Wv   = (const float*)d_in[6];
    const float* bv   = (const float*)d_in[7];
    const float* Wo   = (const float*)d_in[8];
    const float* bo   = (const float*)d_in[9];
    float* out = (float*)d_out;

    const int M = Bb * Ss;  // 4096

    // Workspace (37.75 MB): QO bf16 [M][2048] (16.8 MB) + Wqkv_t bf16
    // [3072][2048] (12.6 MB) + Wo_t bf16 [2048][2048] (8.4 MB).
    bf16* QO    = (bf16*)d_ws;
    bf16* Wqkvt = QO + (size_t)M * (Hh * HD);
    bf16* Wot   = Wqkvt + (size_t)3072 * DMD;

    // d_out scratch (25.2 MB of 33.5 MB): Kb, Vt (front), Abf (middle).
    // All three are dead before the O-projection overwrites d_out.
    bf16* Kb  = (bf16*)d_out;
    bf16* Vt  = Kb + (size_t)M * (KVh * HD);
    bf16* Abf = Vt + (size_t)M * (KVh * HD);

    dim3 blk(256);

    // Prep: hs -> bf16; weights -> K-major bf16 (Wq|Wk|Wv concatenated).
    const int total8 = M * DMD / 8;
    cvt_bf16_kernel<<<(total8 + 255) / 256, blk, 0, stream>>>(hs, Abf, total8);
    cvtT_kernel<<<dim3((Hh * HD) / 32, DMD / 32), blk, 0, stream>>>(
        Wq, Wqkvt, Hh * HD, DMD, 0);
    cvtT_kernel<<<dim3((KVh * HD) / 32, DMD / 32), blk, 0, stream>>>(
        Wk, Wqkvt, KVh * HD, DMD, Hh * HD);
    cvtT_kernel<<<dim3((KVh * HD) / 32, DMD / 32), blk, 0, stream>>>(
        Wv, Wqkvt, KVh * HD, DMD, Hh * HD + KVh * HD);
    cvtT_kernel<<<dim3(DMD / 32, DMD / 32), blk, 0, stream>>>(
        Wo, Wot, DMD, DMD, 0);

    // Fused QKV projection (bf16 in, bf16 staged out; V transposed +bias).
    gemm_bt<0><<<dim3(3072 / 128, M / 128), blk, 0, stream>>>(
        Abf, Wqkvt, bv, QO, Kb, Vt, nullptr, M, 3072, DMD);

    // RoPE (in place; Q gets the 1/sqrt(HD) softmax scale folded in)
    int totq = M * Hh * 32, totk = M * KVh * 32;
    rope_kernel<<<(totq + 255) / 256, blk, 0, stream>>>(QO, cosb, sinb, Hh, totq, 0.125f);
    rope_kernel<<<(totk + 255) / 256, blk, 0, stream>>>(Kb, cosb, sinb, KVh, totk, 1.0f);

    // Flash attention v6 (O overwrites Q in place); 1024 blocks, 1 q-block/wave.
    fattn_kernel<<<dim3(1024), blk, 0, stream>>>(QO, Kb, Vt, mask);

    // Output projection (+bias, fp32 out)
    gemm_bt<1><<<dim3(DMD / 128, M / 128), blk, 0, stream>>>(
        QO, Wot, bo, nullptr, nullptr, nullptr, out, M, DMD, DMD);
}

// Round 7
// 360.289 us; speedup vs baseline: 1.3514x; 1.1930x over previous
//
#include <hip/hip_runtime.h>
#include <hip/hip_bf16.h>

// Problem constants
#define Bb 2
#define Ss 2048
#define DMD 2048
#define Hh 32
#define KVh 8
#define HD 64
// GQA groups = H/KV = 4. Inputs/outputs fp32.

using bf16 = __hip_bfloat16;
typedef __attribute__((ext_vector_type(8))) short short8;
typedef __attribute__((ext_vector_type(4))) float floatx4;

__device__ inline float tof(const bf16 x) { return __bfloat162float(x); }
__device__ inline void stor(float* p, float v) { *p = v; }
__device__ inline void stor(bf16* p, float v) { *p = __float2bfloat16(v); }
__device__ inline short bf16bits(float v) {
    union { bf16 h; short s; } cv; cv.h = __float2bfloat16(v); return cv.s;
}

// global->LDS direct copy, 16 B per lane. LDS destination is the wave-uniform
// base; HW adds lane*16. (guide §5: width=16 is the 874-TF m97 staging path)
__device__ inline void gl_lds16(const bf16* g, bf16* l) {
    __builtin_amdgcn_global_load_lds(
        (const __attribute__((address_space(1))) unsigned int*)g,
        (__attribute__((address_space(3))) unsigned int*)l, 16, 0, 0);
}

// ---------------------------------------------------------------------------
// Prep pass 1: fp32 -> bf16 elementwise (8 elems/thread, float4 loads).
// ---------------------------------------------------------------------------
__global__ __launch_bounds__(256) void cvt_bf16_kernel(
    const float* __restrict__ in, bf16* __restrict__ out, int total8)
{
    const int i = blockIdx.x * 256 + threadIdx.x;
    if (i >= total8) return;
    const float4 a = ((const float4*)in)[2 * i];
    const float4 b = ((const float4*)in)[2 * i + 1];
    short8 r;
    r[0] = bf16bits(a.x); r[1] = bf16bits(a.y); r[2] = bf16bits(a.z); r[3] = bf16bits(a.w);
    r[4] = bf16bits(b.x); r[5] = bf16bits(b.y); r[6] = bf16bits(b.z); r[7] = bf16bits(b.w);
    ((short8*)out)[i] = r;
}

// ---------------------------------------------------------------------------
// Prep pass 2 (single launch): all four weights fp32 [K][N] -> K-major bf16.
// Combined column space: [0,2048) Wq | [2048,2560) Wk | [2560,3072) Wv ->
// Wqkvt rows nc; [3072,5120) Wo -> Wot rows nc-3072. 32x32 LDS tile.
// ---------------------------------------------------------------------------
__global__ __launch_bounds__(256) void cvtT_all_kernel(
    const float* __restrict__ Wq, const float* __restrict__ Wk,
    const float* __restrict__ Wv, const float* __restrict__ Wo,
    bf16* __restrict__ Wqkvt, bf16* __restrict__ Wot)
{
    __shared__ float t[32][33];
    const int nc = blockIdx.x * 32;          // combined col base
    const int k0 = blockIdx.y * 32;
    const float* W; int N, n0, dstRow; bf16* dst;
    if (nc < 2048)      { W = Wq; N = 2048; n0 = nc;        dst = Wqkvt; dstRow = nc; }
    else if (nc < 2560) { W = Wk; N = 512;  n0 = nc - 2048; dst = Wqkvt; dstRow = nc; }
    else if (nc < 3072) { W = Wv; N = 512;  n0 = nc - 2560; dst = Wqkvt; dstRow = nc; }
    else                { W = Wo; N = 2048; n0 = nc - 3072; dst = Wot;   dstRow = nc - 3072; }

    const int tx = threadIdx.x & 31, ty = threadIdx.x >> 5;   // ty 0..7
    #pragma unroll
    for (int r = 0; r < 32; r += 8)
        t[ty + r][tx] = W[(size_t)(k0 + ty + r) * N + n0 + tx];
    __syncthreads();
    #pragma unroll
    for (int r = 0; r < 32; r += 8)
        dst[(size_t)(dstRow + ty + r) * DMD + k0 + tx] =
            __float2bfloat16(t[tx][ty + r]);
}

// ---------------------------------------------------------------------------
// MFMA GEMM, m97 structure: A [M][K] bf16 row-major, Bt [N][K] bf16 K-major.
// 128x128 tile, BK=32, 4 waves x (4x4 16x16x32 tiles), global_load_lds
// width-16 staging into linear [128][32] LDS tiles, 2-barrier loop.
// EPI 0: fused QKV scatter with FUSED ROPE on Q/K:
//   cols [0,2048)   -> Yq, rope applied, x0.125 softmax scale folded
//   cols [2048,2560)-> Yk, rope applied
//   cols [2560,3072)-> Yv transposed [b][kvh][d][s] with +bias
//   (rope pair (d, d+32) = acc cols (j, j+2) — in-register; cos/sin fp32
//    rows indexed by gm = b*S+s, coalesced across lid)
// EPI 1: fp32 out + bias (O projection)
// ---------------------------------------------------------------------------
template <int EPI>
__global__ __launch_bounds__(256) void gemm_bt(
    const bf16* __restrict__ A, const bf16* __restrict__ Bt,
    const float* __restrict__ bias,
    const float* __restrict__ cosb, const float* __restrict__ sinb,
    bf16* __restrict__ Yq, bf16* __restrict__ Yk, bf16* __restrict__ Yv,
    float* __restrict__ Yo, int M, int N, int K)
{
    __shared__ bf16 As[128 * 32];   // [m][k] row-major, chunk ch <-> bytes ch*16
    __shared__ bf16 Bs[128 * 32];   // [n][k] row-major

    const int tid  = threadIdx.x;
    const int wave = tid >> 6, lane = tid & 63;
    const int lid  = lane & 15, quad = lane >> 4;
    const int wr = (wave >> 1) * 64, wc = (wave & 1) * 64;
    const size_t bm = (size_t)blockIdx.y * 128, bn = (size_t)blockIdx.x * 128;

    floatx4 acc[4][4];
    #pragma unroll
    for (int i = 0; i < 4; ++i)
        #pragma unroll
        for (int j = 0; j < 4; ++j)
            acc[i][j] = (floatx4){0.f, 0.f, 0.f, 0.f};

    for (int k0 = 0; k0 < K; k0 += 32) {
        // stage A-tile and B-tile: 512 16B-chunks each; wave covers 128
        // chunks (2 issues). chunk c: row = c>>2, k-col = (c&3)*8.
        #pragma unroll
        for (int i = 0; i < 2; ++i) {
            const int c   = wave * 128 + i * 64 + lane;
            const int row = c >> 2, col = (c & 3) * 8;
            gl_lds16(A  + (bm + row) * (size_t)K + k0 + col,
                     &As[(wave * 128 + i * 64) * 8]);
            gl_lds16(Bt + (bn + row) * (size_t)K + k0 + col,
                     &Bs[(wave * 128 + i * 64) * 8]);
        }
        __syncthreads();

        short8 af[4], bfr[4];
        #pragma unroll
        for (int i = 0; i < 4; ++i)
            af[i] = *(const short8*)&As[(wr + i * 16 + lid) * 32 + quad * 8];
        #pragma unroll
        for (int j = 0; j < 4; ++j)
            bfr[j] = *(const short8*)&Bs[(wc + j * 16 + lid) * 32 + quad * 8];
        #pragma unroll
        for (int i = 0; i < 4; ++i)
            #pragma unroll
            for (int j = 0; j < 4; ++j)
                acc[i][j] = __builtin_amdgcn_mfma_f32_16x16x32_bf16(
                    af[i], bfr[j], acc[i][j], 0, 0, 0);
        __syncthreads();
    }

    if (EPI == 0) {
        const int colbase = (int)bn + wc;      // 64-aligned, wave-uniform
        if (colbase < Hh * HD + KVh * HD) {
            // ---- Q or K: fused rope; pair (d, d+32) = (acc j, acc j+2) ----
            const bool isQ = colbase < Hh * HD;
            const float scale = isQ ? 0.125f : 1.0f;
            #pragma unroll
            for (int i = 0; i < 4; ++i) {
                const int gm0 = (int)bm + wr + i * 16 + quad * 4;
                #pragma unroll
                for (int r = 0; r < 4; ++r) {
                    const int gm = gm0 + r;
                    const float* crow = cosb + (size_t)gm * HD;
                    const float* srow = sinb + (size_t)gm * HD;
                    #pragma unroll
                    for (int jp = 0; jp < 2; ++jp) {
                        const int d1 = jp * 16 + lid;           // < 32
                        const float x1 = acc[i][jp][r];
                        const float x2 = acc[i][jp + 2][r];
                        const float c1 = crow[d1],      s1 = srow[d1];
                        const float c2 = crow[d1 + 32], s2 = srow[d1 + 32];
                        const float y1 = (x1 * c1 - x2 * s1) * scale;
                        const float y2 = (x2 * c2 + x1 * s2) * scale;
                        const int gn1 = colbase + d1;
                        if (isQ) {
                            stor(&Yq[(size_t)gm * (Hh * HD) + gn1],      y1);
                            stor(&Yq[(size_t)gm * (Hh * HD) + gn1 + 32], y2);
                        } else {
                            const int cK = gn1 - Hh * HD;
                            stor(&Yk[(size_t)gm * (KVh * HD) + cK],      y1);
                            stor(&Yk[(size_t)gm * (KVh * HD) + cK + 32], y2);
                        }
                    }
                }
            }
        } else {
            // ---- V: +bias, transpose-scatter [b][kvh][d][s] ----
            #pragma unroll
            for (int i = 0; i < 4; ++i) {
                const int gm0 = (int)bm + wr + i * 16 + quad * 4;
                #pragma unroll
                for (int j = 0; j < 4; ++j) {
                    const int gn = colbase + j * 16 + lid;
                    const int c  = gn - (Hh * HD + KVh * HD);
                    const int kvh = c >> 6, dd = c & 63;
                    #pragma unroll
                    for (int r = 0; r < 4; ++r) {
                        const float v = acc[i][j][r] + bias[c];
                        const int gm = gm0 + r;
                        const int bbi = gm >> 11, s = gm & (Ss - 1);
                        stor(&Yv[(((size_t)bbi * KVh + kvh) * HD + dd) * Ss + s], v);
                    }
                }
            }
        }
    } else {
        #pragma unroll
        for (int i = 0; i < 4; ++i) {
            const int gm0 = (int)bm + wr + i * 16 + quad * 4;
            #pragma unroll
            for (int j = 0; j < 4; ++j) {
                const int gn = (int)bn + wc + j * 16 + lid;
                #pragma unroll
                for (int r = 0; r < 4; ++r)
                    Yo[(size_t)(gm0 + r) * N + gn] = acc[i][j][r] + bias[gn];
            }
        }
    }
}

// ---------------------------------------------------------------------------
// MFMA flash attention v7: v3 tile body, 64 q-rows per wave (4 row-groups).
// Halves total wave-tiles (68k -> 34k) with identical per-tile K/V/mask VMEM
// (the dominant per-tile cost, per v2..v6 evidence). Register pressure
// managed per-group: {QK^T -> softmax -> pLds write} keeps s to 16 regs;
// peak ~200 VGPR -> 2 waves/SIMD, matching the 512-block grid (all blocks
// co-resident: 2 blocks/CU). Block pairing: bid and bid+256 (same CU under
// sequential fill) get complementary qb (sum 7) -> per-CU load balance.
// pLds row pad 76 keeps the P-transpose bank-conflict-free. No barriers.
// ---------------------------------------------------------------------------
template <bool CAUSAL>
__device__ __forceinline__ void fattn_tile64(
    const int k0, const int m0,
    const bf16* __restrict__ kBase, const bf16* __restrict__ vBase,
    const int* __restrict__ mBase,
    const short8 qf0[4], const short8 qf1[4],
    floatx4 o[4][4], float lsum[4][4],
    short (*pw)[16][76],               // -> pLds[wave]: [4][16][76]
    const int lid, const int quad)
{
    const size_t kStride = (size_t)KVh * HD;  // 512 elems

    // ---- K fragments ----
    short8 kb0[4], kb1[4];
    #pragma unroll
    for (int nt = 0; nt < 4; ++nt) {
        const bf16* kr = kBase + (size_t)(k0 + nt * 16 + lid) * kStride + quad * 8;
        kb0[nt] = *(const short8*)(kr);
        kb1[nt] = *(const short8*)(kr + 32);
    }
    // ---- V fragments issue early; latency hides under QK+softmax ----
    short8 vb0[4], vb1[4];
    #pragma unroll
    for (int nt = 0; nt < 4; ++nt) {
        const bf16* vr = vBase + (size_t)(nt * 16 + lid) * Ss + k0 + quad * 8;
        vb0[nt] = *(const short8*)(vr);
        vb1[nt] = *(const short8*)(vr + 32);
    }
    // ---- mask (per-lane col = k0 + nt*16 + lid) ----
    int mk[4];
    #pragma unroll
    for (int nt = 0; nt < 4; ++nt) mk[nt] = mBase[k0 + nt * 16 + lid];

    // ---- per row-group: S = Q K^T -> mask+exp -> pLds write ----
    #pragma unroll
    for (int g = 0; g < 4; ++g) {
        floatx4 s[4];
        __builtin_amdgcn_s_setprio(1);
        #pragma unroll
        for (int nt = 0; nt < 4; ++nt) {
            floatx4 c = (floatx4){0.f, 0.f, 0.f, 0.f};
            c = __builtin_amdgcn_mfma_f32_16x16x32_bf16(qf0[g], kb0[nt], c, 0, 0, 0);
            c = __builtin_amdgcn_mfma_f32_16x16x32_bf16(qf1[g], kb1[nt], c, 0, 0, 0);
            s[nt] = c;
        }
        __builtin_amdgcn_s_setprio(0);
        const int mr0 = m0 + g * 16 + quad * 4;
        #pragma unroll
        for (int nt = 0; nt < 4; ++nt) {
            const int col = k0 + nt * 16 + lid;
            #pragma unroll
            for (int rr = 0; rr < 4; ++rr) {
                float p;
                if (CAUSAL)
                    p = (mk[nt] == 0 || col > mr0 + rr) ? 0.f : __expf(s[nt][rr]);
                else
                    p = (mk[nt] == 0) ? 0.f : __expf(s[nt][rr]);
                lsum[g][rr] += p;
                pw[g][quad * 4 + rr][nt * 16 + lid] = bf16bits(p);
            }
        }
    }

    // ---- per row-group: P fragment read + PV ----
    #pragma unroll
    for (int g = 0; g < 4; ++g) {
        const short8 pf0 = *(const short8*)&pw[g][lid][quad * 8];
        const short8 pf1 = *(const short8*)&pw[g][lid][32 + quad * 8];
        __builtin_amdgcn_s_setprio(1);
        #pragma unroll
        for (int nt = 0; nt < 4; ++nt) {
            o[g][nt] = __builtin_amdgcn_mfma_f32_16x16x32_bf16(
                pf0, vb0[nt], o[g][nt], 0, 0, 0);
            o[g][nt] = __builtin_amdgcn_mfma_f32_16x16x32_bf16(
                pf1, vb1[nt], o[g][nt], 0, 0, 0);
        }
        __builtin_amdgcn_s_setprio(0);
    }
}

__global__ __launch_bounds__(256) void fattn_kernel(
    bf16* __restrict__ QO, const bf16* __restrict__ Kb,
    const bf16* __restrict__ Vt, const int* __restrict__ mask)
{
    const int bid  = blockIdx.x;        // 0..511
    const int kvh  = bid & 7;           // XCD-local K/V reuse
    const int rest = bid >> 3;          // 0..63
    const int low  = rest & 31, half = rest >> 5;
    const int bh   = low & 7;
    const int q3   = low >> 3;          // 0..3
    const int qb   = half ? (7 - 2 * q3) : (2 * q3);   // bid/bid+256 sum to 7
    const int hg   = bh & 3;
    const int b    = bh >> 2;
    const int h    = kvh * 4 + hg;

    const int tid  = threadIdx.x;
    const int wave = tid >> 6;
    const int lane = tid & 63;
    const int lid  = lane & 15;
    const int quad = lane >> 4;

    const int qw = qb * 4 + wave;       // 0..31, this wave's 64-row q-block
    const int m0 = qw * 64;
    const int nfull = qw;               // fully-causal-valid 64-key tiles

    __shared__ short pLds[4][4][16][76];   // per-wave private P transpose

    const size_t kStride = (size_t)KVh * HD;  // 512 elems
    const bf16* kBase = Kb + ((size_t)b * Ss) * kStride + (size_t)kvh * HD;
    const bf16* vBase = Vt + ((size_t)(b * KVh + kvh) * HD) * Ss;
    const int*  mBase = mask + b * Ss;

    // Q fragments for four 16-row groups (pre-scaled by 1/8 in gemm epilogue)
    short8 qf0[4], qf1[4];
    #pragma unroll
    for (int g = 0; g < 4; ++g) {
        const bf16* qb_ = QO + ((size_t)(b * Ss + m0 + g * 16 + lid) * Hh + h) * HD
                        + quad * 8;
        qf0[g] = *(const short8*)(qb_);
        qf1[g] = *(const short8*)(qb_ + 32);
    }

    floatx4 o[4][4];
    float lsum[4][4];
    #pragma unroll
    for (int g = 0; g < 4; ++g) {
        #pragma unroll
        for (int nt = 0; nt < 4; ++nt) o[g][nt] = (floatx4){0.f, 0.f, 0.f, 0.f};
        #pragma unroll
        for (int rr = 0; rr < 4; ++rr) lsum[g][rr] = 0.f;
    }

    // Full tiles: attention_mask check only.
    for (int kt = 0; kt < nfull; ++kt)
        fattn_tile64<false>(kt * 64, m0, kBase, vBase, mBase,
                            qf0, qf1, o, lsum, pLds[wave], lid, quad);
    // Boundary (diagonal) tile: causal + attention_mask.
    fattn_tile64<true>(nfull * 64, m0, kBase, vBase, mBase,
                       qf0, qf1, o, lsum, pLds[wave], lid, quad);

    // ---- epilogue: reduce l across the 16 key-lanes, normalize, store ----
    #pragma unroll
    for (int g = 0; g < 4; ++g)
        #pragma unroll
        for (int rr = 0; rr < 4; ++rr) {
            float rs = lsum[g][rr];
            rs += __shfl_xor(rs, 1);
            rs += __shfl_xor(rs, 2);
            rs += __shfl_xor(rs, 4);
            rs += __shfl_xor(rs, 8);
            const float inv = 1.f / rs;
            const int m = m0 + g * 16 + quad * 4 + rr;
            bf16* orow = QO + ((size_t)(b * Ss + m) * Hh + h) * HD;
            #pragma unroll
            for (int nt = 0; nt < 4; ++nt)
                stor(&orow[nt * 16 + lid], o[g][nt][rr] * inv);
        }
}

// ---------------------------------------------------------------------------
extern "C" void kernel_launch(void* const* d_in, const int* in_sizes, int n_in,
                              void* d_out, int out_size, void* d_ws, size_t ws_size,
                              hipStream_t stream)
{
    const float* hs   = (const float*)d_in[0];
    const int*   mask = (const int*)d_in[1];
    const float* cosb = (const float*)d_in[2];
    const float* sinb = (const float*)d_in[3];
    const float* Wq   = (const float*)d_in[4];
    const float* Wk   = (const float*)d_in[5];
    const float* Wv   = (const float*)d_in[6];
    const float* bv   = (const float*)d_in[7];
    const float* Wo   = (const float*)d_in[8];
    const float* bo   = (const float*)d_in[9];
    float* out = (float*)d_out;

    const int M = Bb * Ss;  // 4096

    // Workspace (37.75 MB): QO bf16 [M][2048] (16.8 MB) + Wqkv_t bf16
    // [3072][2048] (12.6 MB) + Wo_t bf16 [2048][2048] (8.4 MB).
    bf16* QO    = (bf16*)d_ws;
    bf16* Wqkvt = QO + (size_t)M * (Hh * HD);
    bf16* Wot   = Wqkvt + (size_t)3072 * DMD;

    // d_out scratch (25.2 MB of 33.5 MB): Kb, Vt (front), Abf (middle).
    // All three are dead before the O-projection overwrites d_out.
    bf16* Kb  = (bf16*)d_out;
    bf16* Vt  = Kb + (size_t)M * (KVh * HD);
    bf16* Abf = Vt + (size_t)M * (KVh * HD);

    dim3 blk(256);

    // Prep: hs -> bf16; all four weights -> K-major bf16 in ONE launch.
    const int total8 = M * DMD / 8;
    cvt_bf16_kernel<<<(total8 + 255) / 256, blk, 0, stream>>>(hs, Abf, total8);
    cvtT_all_kernel<<<dim3(5120 / 32, DMD / 32), blk, 0, stream>>>(
        Wq, Wk, Wv, Wo, Wqkvt, Wot);

    // Fused QKV projection with fused RoPE on Q (x0.125) and K; V transposed
    // +bias. Q/K land rope'd -> no separate rope kernels.
    gemm_bt<0><<<dim3(3072 / 128, M / 128), blk, 0, stream>>>(
        Abf, Wqkvt, bv, cosb, sinb, QO, Kb, Vt, nullptr, M, 3072, DMD);

    // Flash attention v7 (O overwrites Q in place); 512 blocks, 64 rows/wave.
    fattn_kernel<<<dim3(512), blk, 0, stream>>>(QO, Kb, Vt, mask);

    // Output projection (+bias, fp32 out)
    gemm_bt<1><<<dim3(DMD / 128, M / 128), blk, 0, stream>>>(
        QO, Wot, bo, nullptr, nullptr, nullptr, nullptr, nullptr, out, M, DMD, DMD);
}

// Round 9
// 348.346 us; speedup vs baseline: 1.3978x; 1.0343x over previous
//
#include <hip/hip_runtime.h>
#include <hip/hip_bf16.h>

// Problem constants
#define Bb 2
#define Ss 2048
#define DMD 2048
#define Hh 32
#define KVh 8
#define HD 64
// GQA groups = H/KV = 4. Inputs/outputs fp32.

using bf16 = __hip_bfloat16;
typedef __attribute__((ext_vector_type(8))) short short8;
typedef __attribute__((ext_vector_type(4))) float floatx4;

__device__ inline float tof(const bf16 x) { return __bfloat162float(x); }
__device__ inline void stor(float* p, float v) { *p = v; }
__device__ inline void stor(bf16* p, float v) { *p = __float2bfloat16(v); }
__device__ inline short bf16bits(float v) {
    union { bf16 h; short s; } cv; cv.h = __float2bfloat16(v); return cv.s;
}

// global->LDS direct copy, 16 B per lane. LDS destination is the wave-uniform
// base; HW adds lane*16. (guide §5: width=16 is the 874-TF m97 staging path)
__device__ inline void gl_lds16(const bf16* g, bf16* l) {
    __builtin_amdgcn_global_load_lds(
        (const __attribute__((address_space(1))) unsigned int*)g,
        (__attribute__((address_space(3))) unsigned int*)l, 16, 0, 0);
}

// ---------------------------------------------------------------------------
// Prep pass 1: fp32 -> bf16 elementwise (8 elems/thread, float4 loads).
// ---------------------------------------------------------------------------
__global__ __launch_bounds__(256) void cvt_bf16_kernel(
    const float* __restrict__ in, bf16* __restrict__ out, int total8)
{
    const int i = blockIdx.x * 256 + threadIdx.x;
    if (i >= total8) return;
    const float4 a = ((const float4*)in)[2 * i];
    const float4 b = ((const float4*)in)[2 * i + 1];
    short8 r;
    r[0] = bf16bits(a.x); r[1] = bf16bits(a.y); r[2] = bf16bits(a.z); r[3] = bf16bits(a.w);
    r[4] = bf16bits(b.x); r[5] = bf16bits(b.y); r[6] = bf16bits(b.z); r[7] = bf16bits(b.w);
    ((short8*)out)[i] = r;
}

// ---------------------------------------------------------------------------
// Prep pass 2 (single launch): all four weights fp32 [K][N] -> K-major bf16.
// Combined column space: [0,2048) Wq | [2048,2560) Wk | [2560,3072) Wv ->
// Wqkvt rows nc; [3072,5120) Wo -> Wot rows nc-3072. 32x32 LDS tile.
// ---------------------------------------------------------------------------
__global__ __launch_bounds__(256) void cvtT_all_kernel(
    const float* __restrict__ Wq, const float* __restrict__ Wk,
    const float* __restrict__ Wv, const float* __restrict__ Wo,
    bf16* __restrict__ Wqkvt, bf16* __restrict__ Wot)
{
    __shared__ float t[32][33];
    const int nc = blockIdx.x * 32;          // combined col base
    const int k0 = blockIdx.y * 32;
    const float* W; int N, n0, dstRow; bf16* dst;
    if (nc < 2048)      { W = Wq; N = 2048; n0 = nc;        dst = Wqkvt; dstRow = nc; }
    else if (nc < 2560) { W = Wk; N = 512;  n0 = nc - 2048; dst = Wqkvt; dstRow = nc; }
    else if (nc < 3072) { W = Wv; N = 512;  n0 = nc - 2560; dst = Wqkvt; dstRow = nc; }
    else                { W = Wo; N = 2048; n0 = nc - 3072; dst = Wot;   dstRow = nc - 3072; }

    const int tx = threadIdx.x & 31, ty = threadIdx.x >> 5;   // ty 0..7
    #pragma unroll
    for (int r = 0; r < 32; r += 8)
        t[ty + r][tx] = W[(size_t)(k0 + ty + r) * N + n0 + tx];
    __syncthreads();
    #pragma unroll
    for (int r = 0; r < 32; r += 8)
        dst[(size_t)(dstRow + ty + r) * DMD + k0 + tx] =
            __float2bfloat16(t[tx][ty + r]);
}

// ---------------------------------------------------------------------------
// MFMA GEMM, m97 structure + minimum 2-phase pipeline (guide T3 recipe):
// A [M][K] bf16 row-major, Bt [N][K] bf16 K-major. 128x128 tile, BK=32,
// 4 waves x (4x4 16x16x32 tiles), global_load_lds width-16 staging into
// DOUBLE-BUFFERED linear [128][32] LDS tiles. Tile t+1's loads are issued
// BEFORE tile t's compute, so their latency hides under the 16 MFMAs; one
// __syncthreads per tile (its vmcnt drain covers only the residual).
// Hazards: buffer written at step t was last read at step t-1 (barrier-
// protected); compute at t+1 reads loads issued at t (barrier vmcnt drain).
// EPI 0: fused QKV scatter with FUSED ROPE on Q (x0.125 folded) / K;
//        V transposed [b][kvh][d][s] + bias.
// EPI 1: fp32 out + bias (O projection).
// ---------------------------------------------------------------------------
template <int EPI>
__global__ __launch_bounds__(256) void gemm_bt(
    const bf16* __restrict__ A, const bf16* __restrict__ Bt,
    const float* __restrict__ bias,
    const float* __restrict__ cosb, const float* __restrict__ sinb,
    bf16* __restrict__ Yq, bf16* __restrict__ Yk, bf16* __restrict__ Yv,
    float* __restrict__ Yo, int M, int N, int K)
{
    __shared__ bf16 As[2][128 * 32];   // [buf][m][k], chunk ch <-> bytes ch*16
    __shared__ bf16 Bs[2][128 * 32];   // [buf][n][k]

    const int tid  = threadIdx.x;
    const int wave = tid >> 6, lane = tid & 63;
    const int lid  = lane & 15, quad = lane >> 4;
    const int wr = (wave >> 1) * 64, wc = (wave & 1) * 64;
    const size_t bm = (size_t)blockIdx.y * 128, bn = (size_t)blockIdx.x * 128;

    floatx4 acc[4][4];
    #pragma unroll
    for (int i = 0; i < 4; ++i)
        #pragma unroll
        for (int j = 0; j < 4; ++j)
            acc[i][j] = (floatx4){0.f, 0.f, 0.f, 0.f};

    const int NT = K >> 5;   // K-tiles of 32

    // Stage K-tile t into buffer bufi: 512 16B-chunks each for A and B;
    // wave covers 128 chunks (2 issues). chunk c: row = c>>2, col = (c&3)*8.
    auto stage = [&](int t, int bufi) {
        #pragma unroll
        for (int i = 0; i < 2; ++i) {
            const int c   = wave * 128 + i * 64 + lane;
            const int row = c >> 2, col = (c & 3) * 8;
            gl_lds16(A  + (bm + row) * (size_t)K + t * 32 + col,
                     &As[bufi][(wave * 128 + i * 64) * 8]);
            gl_lds16(Bt + (bn + row) * (size_t)K + t * 32 + col,
                     &Bs[bufi][(wave * 128 + i * 64) * 8]);
        }
    };

    stage(0, 0);
    __syncthreads();                       // buf0 ready (vmcnt drained)

    for (int t = 0; t < NT; ++t) {
        const int cur = t & 1;
        if (t + 1 < NT) stage(t + 1, cur ^ 1);   // issue BEFORE compute

        short8 af[4], bfr[4];
        #pragma unroll
        for (int i = 0; i < 4; ++i)
            af[i] = *(const short8*)&As[cur][(wr + i * 16 + lid) * 32 + quad * 8];
        #pragma unroll
        for (int j = 0; j < 4; ++j)
            bfr[j] = *(const short8*)&Bs[cur][(wc + j * 16 + lid) * 32 + quad * 8];
        #pragma unroll
        for (int i = 0; i < 4; ++i)
            #pragma unroll
            for (int j = 0; j < 4; ++j)
                acc[i][j] = __builtin_amdgcn_mfma_f32_16x16x32_bf16(
                    af[i], bfr[j], acc[i][j], 0, 0, 0);
        __syncthreads();                   // next tile landed; buf reusable
    }

    if (EPI == 0) {
        const int colbase = (int)bn + wc;      // 64-aligned, wave-uniform
        if (colbase < Hh * HD + KVh * HD) {
            // ---- Q or K: fused rope; pair (d, d+32) = (acc j, acc j+2) ----
            const bool isQ = colbase < Hh * HD;
            const float scale = isQ ? 0.125f : 1.0f;
            #pragma unroll
            for (int i = 0; i < 4; ++i) {
                const int gm0 = (int)bm + wr + i * 16 + quad * 4;
                #pragma unroll
                for (int r = 0; r < 4; ++r) {
                    const int gm = gm0 + r;
                    const float* crow = cosb + (size_t)gm * HD;
                    const float* srow = sinb + (size_t)gm * HD;
                    #pragma unroll
                    for (int jp = 0; jp < 2; ++jp) {
                        const int d1 = jp * 16 + lid;           // < 32
                        const float xa = acc[i][jp][r];
                        const float xb = acc[i][jp + 2][r];
                        const float c1 = crow[d1],      s1 = srow[d1];
                        const float c2 = crow[d1 + 32], s2 = srow[d1 + 32];
                        const float y1 = (xa * c1 - xb * s1) * scale;
                        const float y2 = (xb * c2 + xa * s2) * scale;
                        const int gn1 = colbase + d1;
                        if (isQ) {
                            stor(&Yq[(size_t)gm * (Hh * HD) + gn1],      y1);
                            stor(&Yq[(size_t)gm * (Hh * HD) + gn1 + 32], y2);
                        } else {
                            const int cK = gn1 - Hh * HD;
                            stor(&Yk[(size_t)gm * (KVh * HD) + cK],      y1);
                            stor(&Yk[(size_t)gm * (KVh * HD) + cK + 32], y2);
                        }
                    }
                }
            }
        } else {
            // ---- V: +bias, transpose-scatter [b][kvh][d][s] ----
            #pragma unroll
            for (int i = 0; i < 4; ++i) {
                const int gm0 = (int)bm + wr + i * 16 + quad * 4;
                #pragma unroll
                for (int j = 0; j < 4; ++j) {
                    const int gn = colbase + j * 16 + lid;
                    const int c  = gn - (Hh * HD + KVh * HD);
                    const int kvh = c >> 6, dd = c & 63;
                    #pragma unroll
                    for (int r = 0; r < 4; ++r) {
                        const float v = acc[i][j][r] + bias[c];
                        const int gm = gm0 + r;
                        const int bbi = gm >> 11, s = gm & (Ss - 1);
                        stor(&Yv[(((size_t)bbi * KVh + kvh) * HD + dd) * Ss + s], v);
                    }
                }
            }
        }
    } else {
        #pragma unroll
        for (int i = 0; i < 4; ++i) {
            const int gm0 = (int)bm + wr + i * 16 + quad * 4;
            #pragma unroll
            for (int j = 0; j < 4; ++j) {
                const int gn = (int)bn + wc + j * 16 + lid;
                #pragma unroll
                for (int r = 0; r < 4; ++r)
                    Yo[(size_t)(gm0 + r) * N + gn] = acc[i][j][r] + bias[gn];
            }
        }
    }
}

// ---------------------------------------------------------------------------
// MFMA flash attention v7 (unchanged: 118 us measured). v3 tile body, 64
// q-rows per wave (4 row-groups); 512 blocks; kvh = bid%8 XCD pinning;
// causal only on boundary tile; pLds pad 76 (conflict-free); no barriers.
// ---------------------------------------------------------------------------
template <bool CAUSAL>
__device__ __forceinline__ void fattn_tile64(
    const int k0, const int m0,
    const bf16* __restrict__ kBase, const bf16* __restrict__ vBase,
    const int* __restrict__ mBase,
    const short8 qf0[4], const short8 qf1[4],
    floatx4 o[4][4], float lsum[4][4],
    short (*pw)[16][76],               // -> pLds[wave]: [4][16][76]
    const int lid, const int quad)
{
    const size_t kStride = (size_t)KVh * HD;  // 512 elems

    short8 kb0[4], kb1[4];
    #pragma unroll
    for (int nt = 0; nt < 4; ++nt) {
        const bf16* kr = kBase + (size_t)(k0 + nt * 16 + lid) * kStride + quad * 8;
        kb0[nt] = *(const short8*)(kr);
        kb1[nt] = *(const short8*)(kr + 32);
    }
    short8 vb0[4], vb1[4];
    #pragma unroll
    for (int nt = 0; nt < 4; ++nt) {
        const bf16* vr = vBase + (size_t)(nt * 16 + lid) * Ss + k0 + quad * 8;
        vb0[nt] = *(const short8*)(vr);
        vb1[nt] = *(const short8*)(vr + 32);
    }
    int mk[4];
    #pragma unroll
    for (int nt = 0; nt < 4; ++nt) mk[nt] = mBase[k0 + nt * 16 + lid];

    #pragma unroll
    for (int g = 0; g < 4; ++g) {
        floatx4 s[4];
        __builtin_amdgcn_s_setprio(1);
        #pragma unroll
        for (int nt = 0; nt < 4; ++nt) {
            floatx4 c = (floatx4){0.f, 0.f, 0.f, 0.f};
            c = __builtin_amdgcn_mfma_f32_16x16x32_bf16(qf0[g], kb0[nt], c, 0, 0, 0);
            c = __builtin_amdgcn_mfma_f32_16x16x32_bf16(qf1[g], kb1[nt], c, 0, 0, 0);
            s[nt] = c;
        }
        __builtin_amdgcn_s_setprio(0);
        const int mr0 = m0 + g * 16 + quad * 4;
        #pragma unroll
        for (int nt = 0; nt < 4; ++nt) {
            const int col = k0 + nt * 16 + lid;
            #pragma unroll
            for (int rr = 0; rr < 4; ++rr) {
                float p;
                if (CAUSAL)
                    p = (mk[nt] == 0 || col > mr0 + rr) ? 0.f : __expf(s[nt][rr]);
                else
                    p = (mk[nt] == 0) ? 0.f : __expf(s[nt][rr]);
                lsum[g][rr] += p;
                pw[g][quad * 4 + rr][nt * 16 + lid] = bf16bits(p);
            }
        }
    }

    #pragma unroll
    for (int g = 0; g < 4; ++g) {
        const short8 pf0 = *(const short8*)&pw[g][lid][quad * 8];
        const short8 pf1 = *(const short8*)&pw[g][lid][32 + quad * 8];
        __builtin_amdgcn_s_setprio(1);
        #pragma unroll
        for (int nt = 0; nt < 4; ++nt) {
            o[g][nt] = __builtin_amdgcn_mfma_f32_16x16x32_bf16(
                pf0, vb0[nt], o[g][nt], 0, 0, 0);
            o[g][nt] = __builtin_amdgcn_mfma_f32_16x16x32_bf16(
                pf1, vb1[nt], o[g][nt], 0, 0, 0);
        }
        __builtin_amdgcn_s_setprio(0);
    }
}

__global__ __launch_bounds__(256) void fattn_kernel(
    bf16* __restrict__ QO, const bf16* __restrict__ Kb,
    const bf16* __restrict__ Vt, const int* __restrict__ mask)
{
    const int bid  = blockIdx.x;        // 0..511
    const int kvh  = bid & 7;           // XCD-local K/V reuse
    const int rest = bid >> 3;          // 0..63
    const int low  = rest & 31, half = rest >> 5;
    const int bh   = low & 7;
    const int q3   = low >> 3;          // 0..3
    const int qb   = half ? (7 - 2 * q3) : (2 * q3);   // bid/bid+256 sum to 7
    const int hg   = bh & 3;
    const int b    = bh >> 2;
    const int h    = kvh * 4 + hg;

    const int tid  = threadIdx.x;
    const int wave = tid >> 6;
    const int lane = tid & 63;
    const int lid  = lane & 15;
    const int quad = lane >> 4;

    const int qw = qb * 4 + wave;       // 0..31, this wave's 64-row q-block
    const int m0 = qw * 64;
    const int nfull = qw;               // fully-causal-valid 64-key tiles

    __shared__ short pLds[4][4][16][76];   // per-wave private P transpose

    const size_t kStride = (size_t)KVh * HD;  // 512 elems
    const bf16* kBase = Kb + ((size_t)b * Ss) * kStride + (size_t)kvh * HD;
    const bf16* vBase = Vt + ((size_t)(b * KVh + kvh) * HD) * Ss;
    const int*  mBase = mask + b * Ss;

    short8 qf0[4], qf1[4];
    #pragma unroll
    for (int g = 0; g < 4; ++g) {
        const bf16* qb_ = QO + ((size_t)(b * Ss + m0 + g * 16 + lid) * Hh + h) * HD
                        + quad * 8;
        qf0[g] = *(const short8*)(qb_);
        qf1[g] = *(const short8*)(qb_ + 32);
    }

    floatx4 o[4][4];
    float lsum[4][4];
    #pragma unroll
    for (int g = 0; g < 4; ++g) {
        #pragma unroll
        for (int nt = 0; nt < 4; ++nt) o[g][nt] = (floatx4){0.f, 0.f, 0.f, 0.f};
        #pragma unroll
        for (int rr = 0; rr < 4; ++rr) lsum[g][rr] = 0.f;
    }

    for (int kt = 0; kt < nfull; ++kt)
        fattn_tile64<false>(kt * 64, m0, kBase, vBase, mBase,
                            qf0, qf1, o, lsum, pLds[wave], lid, quad);
    fattn_tile64<true>(nfull * 64, m0, kBase, vBase, mBase,
                       qf0, qf1, o, lsum, pLds[wave], lid, quad);

    #pragma unroll
    for (int g = 0; g < 4; ++g)
        #pragma unroll
        for (int rr = 0; rr < 4; ++rr) {
            float rs = lsum[g][rr];
            rs += __shfl_xor(rs, 1);
            rs += __shfl_xor(rs, 2);
            rs += __shfl_xor(rs, 4);
            rs += __shfl_xor(rs, 8);
            const float inv = 1.f / rs;
            const int m = m0 + g * 16 + quad * 4 + rr;
            bf16* orow = QO + ((size_t)(b * Ss + m) * Hh + h) * HD;
            #pragma unroll
            for (int nt = 0; nt < 4; ++nt)
                stor(&orow[nt * 16 + lid], o[g][nt][rr] * inv);
        }
}

// ---------------------------------------------------------------------------
extern "C" void kernel_launch(void* const* d_in, const int* in_sizes, int n_in,
                              void* d_out, int out_size, void* d_ws, size_t ws_size,
                              hipStream_t stream)
{
    const float* hs   = (const float*)d_in[0];
    const int*   mask = (const int*)d_in[1];
    const float* cosb = (const float*)d_in[2];
    const float* sinb = (const float*)d_in[3];
    const float* Wq   = (const float*)d_in[4];
    const float* Wk   = (const float*)d_in[5];
    const float* Wv   = (const float*)d_in[6];
    const float* bv   = (const float*)d_in[7];
    const float* Wo   = (const float*)d_in[8];
    const float* bo   = (const float*)d_in[9];
    float* out = (float*)d_out;

    const int M = Bb * Ss;  // 4096

    // Workspace (37.75 MB): QO bf16 [M][2048] (16.8 MB) + Wqkv_t bf16
    // [3072][2048] (12.6 MB) + Wo_t bf16 [2048][2048] (8.4 MB).
    bf16* QO    = (bf16*)d_ws;
    bf16* Wqkvt = QO + (size_t)M * (Hh * HD);
    bf16* Wot   = Wqkvt + (size_t)3072 * DMD;

    // d_out scratch (25.2 MB of 33.5 MB): Kb, Vt (front), Abf (middle).
    // All three are dead before the O-projection overwrites d_out.
    bf16* Kb  = (bf16*)d_out;
    bf16* Vt  = Kb + (size_t)M * (KVh * HD);
    bf16* Abf = Vt + (size_t)M * (KVh * HD);

    dim3 blk(256);

    // Prep: hs -> bf16; all four weights -> K-major bf16 in ONE launch.
    const int total8 = M * DMD / 8;
    cvt_bf16_kernel<<<(total8 + 255) / 256, blk, 0, stream>>>(hs, Abf, total8);
    cvtT_all_kernel<<<dim3(5120 / 32, DMD / 32), blk, 0, stream>>>(
        Wq, Wk, Wv, Wo, Wqkvt, Wot);

    // Fused QKV projection with fused RoPE on Q (x0.125) and K; V transposed
    // +bias. 2-phase pipelined staging.
    gemm_bt<0><<<dim3(3072 / 128, M / 128), blk, 0, stream>>>(
        Abf, Wqkvt, bv, cosb, sinb, QO, Kb, Vt, nullptr, M, 3072, DMD);

    // Flash attention v7 (O overwrites Q in place); 512 blocks, 64 rows/wave.
    fattn_kernel<<<dim3(512), blk, 0, stream>>>(QO, Kb, Vt, mask);

    // Output projection (+bias, fp32 out; 2-phase pipelined staging).
    gemm_bt<1><<<dim3(DMD / 128, M / 128), blk, 0, stream>>>(
        QO, Wot, bo, nullptr, nullptr, nullptr, nullptr, nullptr, out, M, DMD, DMD);
}